// Round 12
// baseline (566.199 us; speedup 1.0000x reference)
//
#include <hip/hip_runtime.h>
#include <hip/hip_bf16.h>

typedef __attribute__((ext_vector_type(8))) short short8;
typedef __attribute__((ext_vector_type(4))) float floatx4;

using bf16 = __hip_bfloat16;

__device__ __forceinline__ void cp16_g2l(bf16* lds_p, const bf16* g) {
  __builtin_amdgcn_global_load_lds(
      (const __attribute__((address_space(1))) unsigned int*)g,
      (__attribute__((address_space(3))) unsigned int*)lds_p,
      16, 0, 0);
}

__device__ __forceinline__ float gelu_exact(float x) {
  return 0.5f * x * (1.0f + erff(x * 0.70710678118654752f));
}

// ---------------------------------------------------------------------------
// 128x128 tile GEMM, BK=32, 4 waves, mfma_f32_16x16x32_bf16.
// r12: ring-2 BARRIER-FIRST schedule, 32 KiB LDS -> 4 blocks/CU (was ring-3
// 48 KiB -> 3 blocks/CU; occupancy was the binding resource at 34%).
//   iter t: s_barrier                       // seals reads of tile t-1
//           stage(t+1) -> buf (t+1)&1       // that buf held tile t-1: safe
//           s_waitcnt vmcnt(4)              // tile t landed, t+1 in flight
//           ds_read(t); MFMA(t)
// Ledger (4 loads/thread/step, FIFO): after stage(t+1), outstanding = 4
// (tile t+1 only) -> vmcnt(4) == tile t fully landed. Counted wait never
// drains mid-loop (T4). Ring-2 is sound ONLY with barrier-first ordering:
// the barrier at iter t start guarantees every wave consumed tile t-1
// (its MFMAs issued, so its ds_reads completed) before any wave's
// global_load_lds writes tile t+1 into that buffer.
// NO XCD swizzle (r10: 4.3x FETCH blowup -- per-XCD chunk thrashes 4MiB L2).
// T2 swizzle (rule #21): 16B slot u of row r at physical u^((r>>1)&3).
// Panel-16 layout for P: elem(row,col) at (col>>4)*(PR*16)+row*16+(col&15).
// MODE 0: bf16 = acc + bias                      (QKV)
// MODE 4: bf16 = gelu(acc + bias)                (fc)
// MODE 5: bf16 = acc / rowsum                    (PV; A from panel-16;
//         rowsum via ones-MFMA accs[m][r]; fragment rows == writer rows)
// MODE 6: bf16 = exp(acc*scale) to panel-16      (scores; stride N*16)
// MODE 7: bf16 = acc + bias + f32 resid          (Wo -> bf16 x1)
// MODE 8: f32  = acc + bias + bf16 resid         (proj -> d_out)
// ---------------------------------------------------------------------------
template<int MODE>
__global__ __launch_bounds__(256)
void gemm_bt(const bf16* __restrict__ A, long sAb, long lda,
             const bf16* __restrict__ Bt, long sBb, long ldb,
             const float* __restrict__ bias,
             const float* __restrict__ residf,
             const bf16* __restrict__ residb,
             void* __restrict__ out, long sOb,
             int N, int K, float scale)
{
  constexpr bool PA   = (MODE == 5);   // A operand in panel-16 layout
  constexpr bool ONES = (MODE == 5);   // row-sum via ones-MFMA

  __shared__ __attribute__((aligned(16))) bf16 sA[2][128 * 32];  // 16 KiB
  __shared__ __attribute__((aligned(16))) bf16 sB[2][128 * 32];  // 16 KiB

  const int tid = threadIdx.x;
  const int l = tid & 63, w = tid >> 6;
  const int bz = blockIdx.z;
  const long row0 = (long)blockIdx.x * 128;
  const long col0 = (long)blockIdx.y * 128;

  const bf16* Ab = A + (long)bz * sAb;
  const bf16* Bb = Bt + (long)bz * sBb;

  // staging: wave w covers rows [w*16,+16) and [+64); 4x 16B slots per row
  const int sr = (w << 4) + (l >> 2);                  // 0..63
  const int slot = (l & 3) ^ ((sr >> 1) & 3);          // inverse-swizzled src
  const int kcd = (l & 3) << 3;                        // lane-linear dest
  const bf16* gA;
  long skipA, koA;
  if constexpr (PA) {
    gA    = Ab + ((long)(slot >> 1) * lda + row0 + sr) * 16 + ((slot & 1) << 3);
    skipA = 64 * 16;          // +64 rows within a panel
    koA   = 32 * lda;         // per-K-step advance (2 panels)
  } else {
    gA    = Ab + (row0 + sr) * lda + (slot << 3);
    skipA = 64 * lda;
    koA   = 32;
  }
  const bf16* gB = Bb + (col0 + sr) * ldb + (slot << 3);
  const long skipB = 64 * ldb;
  const int lofs = sr * 32 + kcd;

  floatx4 acc[4][4];
  #pragma unroll
  for (int i = 0; i < 4; ++i)
    #pragma unroll
    for (int j = 0; j < 4; ++j)
      acc[i][j] = (floatx4){0.f, 0.f, 0.f, 0.f};
  floatx4 accs[4];
  #pragma unroll
  for (int i = 0; i < 4; ++i) accs[i] = (floatx4){0.f, 0.f, 0.f, 0.f};
  const short8 b_ones = {0x3F80, 0x3F80, 0x3F80, 0x3F80,
                         0x3F80, 0x3F80, 0x3F80, 0x3F80};  // bf16 1.0 x8

  const int wr = (w >> 1) & 1, wc = w & 1;
  const int g = l >> 4, t = l & 15;
  const int swz = (g ^ ((t >> 1) & 3)) << 3;           // swizzled ds_read slot
  const int aoff = (wr * 64 + t) * 32 + swz;
  const int boff = (wc * 64 + t) * 32 + swz;

  const int nt = K >> 5;

  // prologue: stage tile 0 into buf 0 (4 loads in flight)
  cp16_g2l(&sA[0][lofs],           gA);
  cp16_g2l(&sA[0][lofs] + 64 * 32, gA + skipA);
  cp16_g2l(&sB[0][lofs],           gB);
  cp16_g2l(&sB[0][lofs] + 64 * 32, gB + skipB);

  for (int kt = 0; kt < nt; ++kt) {
    const int cur = kt & 1;
    asm volatile("s_barrier" ::: "memory");  // seals reads of tile kt-1
    if (kt + 1 < nt) {
      const long oA = (long)(kt + 1) * koA;
      const long oB = (long)(kt + 1) << 5;
      bf16* dA = &sA[cur ^ 1][lofs];
      bf16* dB = &sB[cur ^ 1][lofs];
      cp16_g2l(dA,           gA + oA);
      cp16_g2l(dA + 64 * 32, gA + oA + skipA);
      cp16_g2l(dB,           gB + oB);
      cp16_g2l(dB + 64 * 32, gB + oB + skipB);
      asm volatile("s_waitcnt vmcnt(4)" ::: "memory");  // tile kt landed
    } else {
      asm volatile("s_waitcnt vmcnt(0)" ::: "memory");  // final tile landed
    }

    const bf16* cA = &sA[cur][0];
    const bf16* cB = &sB[cur][0];
    short8 a[4], b[4];
    #pragma unroll
    for (int m = 0; m < 4; ++m) a[m] = *(const short8*)(cA + aoff + m * 512);
    #pragma unroll
    for (int n = 0; n < 4; ++n) b[n] = *(const short8*)(cB + boff + n * 512);
    #pragma unroll
    for (int m = 0; m < 4; ++m)
      #pragma unroll
      for (int n = 0; n < 4; ++n)
        acc[m][n] = __builtin_amdgcn_mfma_f32_16x16x32_bf16(a[m], b[n], acc[m][n], 0, 0, 0);
    if constexpr (ONES) {
      #pragma unroll
      for (int m = 0; m < 4; ++m)
        accs[m] = __builtin_amdgcn_mfma_f32_16x16x32_bf16(a[m], b_ones, accs[m], 0, 0, 0);
    }
  }

  // epilogue: C/D layout col = lane&15, row = (lane>>4)*4 + r  [m89]
  const long orow = row0 + wr * 64 + (g << 2);
  const long ocol = col0 + wc * 64 + t;

  if constexpr (MODE == 0 || MODE == 4) {
    bf16* O = (bf16*)out + (long)bz * sOb;
    float bv4[4];
    #pragma unroll
    for (int n = 0; n < 4; ++n) bv4[n] = bias[ocol + n * 16];
    #pragma unroll
    for (int m = 0; m < 4; ++m) {
      #pragma unroll
      for (int r = 0; r < 4; ++r) {
        bf16* Or = O + (orow + m * 16 + r) * (long)N + ocol;
        #pragma unroll
        for (int n = 0; n < 4; ++n) {      // n innermost: row-dense stores
          float vv = acc[m][n][r] + bv4[n];
          if constexpr (MODE == 4) vv = gelu_exact(vv);
          Or[n * 16] = __float2bfloat16(vv);
        }
      }
    }
  } else if constexpr (MODE == 7) {        // bf16 = acc + bias + f32 resid
    bf16* O = (bf16*)out;
    float bv4[4];
    #pragma unroll
    for (int n = 0; n < 4; ++n) bv4[n] = bias[ocol + n * 16];
    #pragma unroll
    for (int m = 0; m < 4; ++m) {
      #pragma unroll
      for (int r = 0; r < 4; ++r) {
        const long rb = (orow + m * 16 + r) * (long)N + ocol;
        #pragma unroll
        for (int n = 0; n < 4; ++n)
          O[rb + n * 16] =
              __float2bfloat16(acc[m][n][r] + bv4[n] + residf[rb + n * 16]);
      }
    }
  } else if constexpr (MODE == 8) {        // f32 = acc + bias + bf16 resid
    float* O = (float*)out;
    float bv4[4];
    #pragma unroll
    for (int n = 0; n < 4; ++n) bv4[n] = bias[ocol + n * 16];
    #pragma unroll
    for (int m = 0; m < 4; ++m) {
      #pragma unroll
      for (int r = 0; r < 4; ++r) {
        const long rb = (orow + m * 16 + r) * (long)N + ocol;
        #pragma unroll
        for (int n = 0; n < 4; ++n)
          O[rb + n * 16] = acc[m][n][r] + bv4[n] +
                           __bfloat162float(residb[rb + n * 16]);
      }
    }
  } else if constexpr (MODE == 5) {
    bf16* O = (bf16*)out + (long)bz * sOb;
    #pragma unroll
    for (int m = 0; m < 4; ++m) {
      #pragma unroll
      for (int r = 0; r < 4; ++r) {
        const long rr = orow + m * 16 + r;
        const float inv = 1.0f / accs[m][r];   // ones-MFMA row sum (exact
        bf16* Or = O + rr * (long)N + ocol;    // same rows as this lane)
        #pragma unroll
        for (int n = 0; n < 4; ++n)
          Or[n * 16] = __float2bfloat16(acc[m][n][r] * inv);
      }
    }
  } else {  // MODE 6: panel-16 exp output; panel stride = N*16 (N == P rows)
    bf16* O = (bf16*)out + (long)bz * sOb;
    const long pb = (col0 >> 4) + wc * 4;              // panel index base
    #pragma unroll
    for (int n = 0; n < 4; ++n) {                      // n outer: panel-dense
      bf16* Opan = O + (pb + n) * ((long)N * 16) + t;
      #pragma unroll
      for (int m = 0; m < 4; ++m) {
        #pragma unroll
        for (int r = 0; r < 4; ++r)
          Opan[(orow + m * 16 + r) * 16] =
              __float2bfloat16(__expf(acc[m][n][r] * scale));
      }
    }
  }
}

// row LayerNorm over D=768, fp32 in -> bf16 out
__global__ __launch_bounds__(256)
void ln_kernel(const float* __restrict__ X, const float* __restrict__ G,
               const float* __restrict__ Bv, bf16* __restrict__ H)
{
  const int tid = threadIdx.x;
  const long row = blockIdx.x;
  const float* xr = X + row * 768;
  const float v0 = xr[tid], v1 = xr[tid + 256], v2 = xr[tid + 512];
  float s = v0 + v1 + v2;
  float s2 = v0 * v0 + v1 * v1 + v2 * v2;
  #pragma unroll
  for (int o = 32; o > 0; o >>= 1) {
    s += __shfl_xor(s, o);
    s2 += __shfl_xor(s2, o);
  }
  __shared__ float red[8];
  const int w = tid >> 6, l = tid & 63;
  if (l == 0) { red[w] = s; red[w + 4] = s2; }
  __syncthreads();
  s = red[0] + red[1] + red[2] + red[3];
  s2 = red[4] + red[5] + red[6] + red[7];
  const float mu = s * (1.f / 768.f);
  const float var = s2 * (1.f / 768.f) - mu * mu;
  const float rstd = rsqrtf(var + 1e-5f);
  bf16* hr = H + row * 768;
  hr[tid]       = __float2bfloat16((v0 - mu) * rstd * G[tid]       + Bv[tid]);
  hr[tid + 256] = __float2bfloat16((v1 - mu) * rstd * G[tid + 256] + Bv[tid + 256]);
  hr[tid + 512] = __float2bfloat16((v2 - mu) * rstd * G[tid + 512] + Bv[tid + 512]);
}

// row LayerNorm over D=768, bf16 in -> bf16 out
__global__ __launch_bounds__(256)
void lnb_kernel(const bf16* __restrict__ X, const float* __restrict__ G,
                const float* __restrict__ Bv, bf16* __restrict__ H)
{
  const int tid = threadIdx.x;
  const long row = blockIdx.x;
  const bf16* xr = X + row * 768;
  const float v0 = __bfloat162float(xr[tid]);
  const float v1 = __bfloat162float(xr[tid + 256]);
  const float v2 = __bfloat162float(xr[tid + 512]);
  float s = v0 + v1 + v2;
  float s2 = v0 * v0 + v1 * v1 + v2 * v2;
  #pragma unroll
  for (int o = 32; o > 0; o >>= 1) {
    s += __shfl_xor(s, o);
    s2 += __shfl_xor(s2, o);
  }
  __shared__ float red[8];
  const int w = tid >> 6, l = tid & 63;
  if (l == 0) { red[w] = s; red[w + 4] = s2; }
  __syncthreads();
  s = red[0] + red[1] + red[2] + red[3];
  s2 = red[4] + red[5] + red[6] + red[7];
  const float mu = s * (1.f / 768.f);
  const float var = s2 * (1.f / 768.f) - mu * mu;
  const float rstd = rsqrtf(var + 1e-5f);
  bf16* hr = H + row * 768;
  hr[tid]       = __float2bfloat16((v0 - mu) * rstd * G[tid]       + Bv[tid]);
  hr[tid + 256] = __float2bfloat16((v1 - mu) * rstd * G[tid + 256] + Bv[tid + 256]);
  hr[tid + 512] = __float2bfloat16((v2 - mu) * rstd * G[tid + 512] + Bv[tid + 512]);
}

// Wt[n][k] = bf16(W[k][n]) ; W fp32 [K][N]. block (32,8)
__global__ void transpose_w(const float* __restrict__ W, bf16* __restrict__ Wt,
                            int K, int N)
{
  __shared__ float tile[32][33];
  const int n0 = blockIdx.x * 32, k0 = blockIdx.y * 32;
  const int tx = threadIdx.x, ty = threadIdx.y;
  #pragma unroll
  for (int j = ty; j < 32; j += 8)
    tile[j][tx] = W[(long)(k0 + j) * N + n0 + tx];
  __syncthreads();
  #pragma unroll
  for (int j = ty; j < 32; j += 8)
    Wt[(long)(n0 + j) * K + k0 + tx] = __float2bfloat16(tile[tx][j]);
}

// Vt[b][d][s] = qkv[(b*2048+s)*2304 + 1536 + d]  (bf16 v-slice of fused qkv)
__global__ void transpose_v(const bf16* __restrict__ QKV, bf16* __restrict__ Vt)
{
  __shared__ bf16 tile[32][33];
  const int d0 = blockIdx.x * 32, s0 = blockIdx.y * 32, b = blockIdx.z;
  const int tx = threadIdx.x, ty = threadIdx.y;
  #pragma unroll
  for (int j = ty; j < 32; j += 8)
    tile[j][tx] = QKV[((long)b * 2048 + s0 + j) * 2304 + 1536 + d0 + tx];
  __syncthreads();
  #pragma unroll
  for (int j = ty; j < 32; j += 8)
    Vt[(long)b * 768 * 2048 + (long)(d0 + j) * 2048 + s0 + tx] = tile[tx][j];
}

// concat 3x768 fp32 biases
__global__ void concat3(const float* __restrict__ a, const float* __restrict__ b,
                        const float* __restrict__ c, float* __restrict__ o)
{
  const int i = threadIdx.x + blockIdx.x * 256;
  if (i < 768) { o[i] = a[i]; o[i + 768] = b[i]; o[i + 1536] = c[i]; }
}

extern "C" void kernel_launch(void* const* d_in, const int* in_sizes, int n_in,
                              void* d_out, int out_size, void* d_ws, size_t ws_size,
                              hipStream_t stream)
{
  const float* x     = (const float*)d_in[0];
  const float* ln1g  = (const float*)d_in[1];
  const float* ln1b  = (const float*)d_in[2];
  const float* ln2g  = (const float*)d_in[3];
  const float* ln2b  = (const float*)d_in[4];
  const float* Wq    = (const float*)d_in[5];
  const float* bq    = (const float*)d_in[6];
  const float* Wk    = (const float*)d_in[7];
  const float* bk    = (const float*)d_in[8];
  const float* Wv    = (const float*)d_in[9];
  const float* bvv   = (const float*)d_in[10];
  const float* Wo    = (const float*)d_in[11];
  const float* bo    = (const float*)d_in[12];
  const float* Wfc   = (const float*)d_in[13];
  const float* bfc   = (const float*)d_in[14];
  const float* Wproj = (const float*)d_in[15];
  const float* bproj = (const float*)d_in[16];
  float* out = (float*)d_out;

  constexpr int Bz = 8, S = 2048, D = 768, Hh = 3072, QKVN = 3 * D;
  constexpr long Mtot = (long)Bz * S;  // 16384

  char* ws = (char*)d_ws;
  size_t off = 0;
  auto alloc = [&](size_t bytes) -> char* {
    char* p = ws + off;
    off += (bytes + 255) & ~(size_t)255;
    return p;
  };
  bf16* wqkvT = (bf16*)alloc((size_t)QKVN * D * 2);
  bf16* woT   = (bf16*)alloc((size_t)D * D * 2);
  bf16* wfcT  = (bf16*)alloc((size_t)Hh * D * 2);
  bf16* wprT  = (bf16*)alloc((size_t)D * Hh * 2);
  float* bqkv = (float*)alloc((size_t)QKVN * 4);
  bf16* hb    = (bf16*)alloc((size_t)Mtot * D * 2);
  bf16* qkv   = (bf16*)alloc((size_t)Mtot * QKVN * 2);
  bf16* vtb   = (bf16*)alloc((size_t)Mtot * D * 2);
  bf16* yb    = (bf16*)alloc((size_t)Mtot * D * 2);
  // x1 (bf16 residual stream) ALIASES qkv: qkv is dead after the last scores
  // GEMM; Wo (which writes x1) launches strictly after it.
  bf16* x1b = qkv;

  int nbat = Bz;
  size_t region = (size_t)nbat * S * S * 2;              // p (bf16, panel-16)
  const size_t mbytes = (size_t)Mtot * Hh * 2;           // MLP hidden bf16
  if (region < mbytes) region = mbytes;
  if (off + region > ws_size) {                          // fallback: per-batch
    nbat = 1;
    region = mbytes;
  }
  char* reg = alloc(region);
  bf16* attn = (bf16*)reg;
  bf16* mb = (bf16*)reg;  // aliases attn (used after attention done)

  const dim3 tb(32, 8);

  // weight prep (bf16, [N][K]); q/k/v stacked into wqkvT rows 0/768/1536
  transpose_w<<<dim3(D / 32, D / 32), tb, 0, stream>>>(Wq, wqkvT, D, D);
  transpose_w<<<dim3(D / 32, D / 32), tb, 0, stream>>>(Wk, wqkvT + (size_t)D * D, D, D);
  transpose_w<<<dim3(D / 32, D / 32), tb, 0, stream>>>(Wv, wqkvT + 2 * (size_t)D * D, D, D);
  transpose_w<<<dim3(D / 32, D / 32), tb, 0, stream>>>(Wo, woT, D, D);
  transpose_w<<<dim3(Hh / 32, D / 32), tb, 0, stream>>>(Wfc, wfcT, D, Hh);
  transpose_w<<<dim3(D / 32, Hh / 32), tb, 0, stream>>>(Wproj, wprT, Hh, D);
  concat3<<<3, 256, 0, stream>>>(bq, bk, bvv, bqkv);

  // LN1 -> h (bf16)
  ln_kernel<<<(int)Mtot, 256, 0, stream>>>(x, ln1g, ln1b, hb);

  // fused QKV projection: [16384,768] @ [2304,768]^T -> [16384,2304]
  gemm_bt<0><<<dim3(Mtot / 128, QKVN / 128, 1), 256, 0, stream>>>(
      hb, 0, D, wqkvT, 0, D, bqkv, nullptr, nullptr, qkv, 0, QKVN, D, 1.f);
  transpose_v<<<dim3(D / 32, S / 32, Bz), tb, 0, stream>>>(qkv, vtb);

  // attention: p = exp(QK^T*sc) (panel-16) -> PV with ones-MFMA row-sums
  const float sc = 0.03608439182435161f;  // 1/sqrt(768)
  for (int g0 = 0; g0 < Bz; g0 += nbat) {
    const bf16* qg  = qkv + (long)g0 * S * QKVN;          // q slice, lda=2304
    const bf16* kg  = qkv + (long)g0 * S * QKVN + D;      // k slice, ldb=2304
    const bf16* vtg = vtb + (long)g0 * D * S;
    bf16* yg = yb + (long)g0 * S * D;
    gemm_bt<6><<<dim3(S / 128, S / 128, nbat), 256, 0, stream>>>(
        qg, (long)S * QKVN, QKVN, kg, (long)S * QKVN, QKVN, nullptr, nullptr,
        nullptr, attn, (long)S * S, S, D, sc);
    gemm_bt<5><<<dim3(S / 128, D / 128, nbat), 256, 0, stream>>>(
        attn, (long)S * S, S, vtg, (long)D * S, S, nullptr, nullptr,
        nullptr, yg, (long)S * D, D, S, 1.f);
  }

  // out-projection + residual -> x1 (bf16 residual stream, aliases dead qkv)
  gemm_bt<7><<<dim3(Mtot / 128, D / 128, 1), 256, 0, stream>>>(
      yb, 0, D, woT, 0, D, bo, x, nullptr, x1b, 0, D, D, 1.f);

  // LN2 -> h2 (bf16, reuse hb)
  lnb_kernel<<<(int)Mtot, 256, 0, stream>>>(x1b, ln2g, ln2b, hb);

  // MLP: fc + exact GELU -> mb (bf16), then proj + bf16 resid -> f32 d_out
  gemm_bt<4><<<dim3(Mtot / 128, Hh / 128, 1), 256, 0, stream>>>(
      hb, 0, D, wfcT, 0, D, bfc, nullptr, nullptr, mb, 0, Hh, D, 1.f);
  gemm_bt<8><<<dim3(Mtot / 128, D / 128, 1), 256, 0, stream>>>(
      mb, 0, Hh, wprT, 0, Hh, bproj, nullptr, x1b, out, 0, D, Hh, 1.f);
}

// Round 13
// 554.296 us; speedup vs baseline: 1.0215x; 1.0215x over previous
//
#include <hip/hip_runtime.h>
#include <hip/hip_bf16.h>

typedef __attribute__((ext_vector_type(8))) short short8;
typedef __attribute__((ext_vector_type(4))) float floatx4;

using bf16 = __hip_bfloat16;

__device__ __forceinline__ void cp16_g2l(bf16* lds_p, const bf16* g) {
  __builtin_amdgcn_global_load_lds(
      (const __attribute__((address_space(1))) unsigned int*)g,
      (__attribute__((address_space(3))) unsigned int*)lds_p,
      16, 0, 0);
}

__device__ __forceinline__ float gelu_exact(float x) {
  return 0.5f * x * (1.0f + erff(x * 0.70710678118654752f));
}

// ---------------------------------------------------------------------------
// 128x128 tile GEMM, BK=32, 4 waves, mfma_f32_16x16x32_bf16.
// Ring-3 LDS (48 KiB) + counted vmcnt(4) -- measured optimum of 5 sync
// variants (r5 drain / r3 ring-4 / r4 8-phase / r8 ring-3 / r12 ring-2):
//   iter t: stage(t+1 -> buf (t+1)%3); vmcnt(4); s_barrier; ds_read(t); MFMA.
//   Ledger (4 loads/thread/step, FIFO): after stage, 8 outstanding;
//   vmcnt(4) == tile t landed, t+1 in flight (never drains mid-loop, T4).
//   Race: reads of t-1 are in epoch (b_{t-1}, b_t); buf (t+1)%3 differs
//   from bufs t%3,(t-1)%3; its old tile t-2 sealed by b_{t-1}.
// r12 falsified the occupancy lever: 32 KiB ring-2 left occupancy at 34%
// and cost 3% (barrier-first ordering shrinks the stage->wait overlap).
// NO XCD swizzle (r10: 4.3x FETCH blowup -- per-XCD chunk thrashes 4MiB L2).
// T2 swizzle (rule #21): 16B slot u of row r at physical u^((r>>1)&3);
// lane-linear gload_lds dest, inverse-swizzled global SOURCE, XORed ds_read.
// Panel-16 layout for P: elem(row,col) at (col>>4)*(PR*16)+row*16+(col&15),
// PR = P row count. MODE 6 writes panels with stride N*16 (N == PR there);
// MODE 5 stages A from panels with PR = lda.
// MODE 0: bf16 = acc + bias                      (QKV)
// MODE 4: bf16 = gelu(acc + bias)                (fc)
// MODE 5: bf16 = acc / rowsum                    (PV; A from panel-16;
//         rowsum via ones-MFMA accs[m][r]; fragment rows == writer rows)
// MODE 6: bf16 = exp(acc*scale) to panel-16      (scores)
// MODE 7: bf16 = acc + bias + f32 resid          (Wo -> bf16 x1)
// MODE 8: f32  = acc + bias + bf16 resid         (proj -> d_out)
// ---------------------------------------------------------------------------
template<int MODE>
__global__ __launch_bounds__(256)
void gemm_bt(const bf16* __restrict__ A, long sAb, long lda,
             const bf16* __restrict__ Bt, long sBb, long ldb,
             const float* __restrict__ bias,
             const float* __restrict__ residf,
             const bf16* __restrict__ residb,
             void* __restrict__ out, long sOb,
             int N, int K, float scale)
{
  constexpr bool PA   = (MODE == 5);   // A operand in panel-16 layout
  constexpr bool ONES = (MODE == 5);   // row-sum via ones-MFMA

  __shared__ __attribute__((aligned(16))) bf16 sA[3][128 * 32];
  __shared__ __attribute__((aligned(16))) bf16 sB[3][128 * 32];

  const int tid = threadIdx.x;
  const int l = tid & 63, w = tid >> 6;
  const int bz = blockIdx.z;
  const long row0 = (long)blockIdx.x * 128;
  const long col0 = (long)blockIdx.y * 128;

  const bf16* Ab = A + (long)bz * sAb;
  const bf16* Bb = Bt + (long)bz * sBb;

  // staging: wave w covers rows [w*16,+16) and [+64); 4x 16B slots per row
  const int sr = (w << 4) + (l >> 2);                  // 0..63
  const int slot = (l & 3) ^ ((sr >> 1) & 3);          // inverse-swizzled src
  const int kcd = (l & 3) << 3;                        // lane-linear dest
  const bf16* gA;
  long skipA, koA;
  if constexpr (PA) {
    gA    = Ab + ((long)(slot >> 1) * lda + row0 + sr) * 16 + ((slot & 1) << 3);
    skipA = 64 * 16;          // +64 rows within a panel
    koA   = 32 * lda;         // per-K-step advance (2 panels)
  } else {
    gA    = Ab + (row0 + sr) * lda + (slot << 3);
    skipA = 64 * lda;
    koA   = 32;
  }
  const bf16* gB = Bb + (col0 + sr) * ldb + (slot << 3);
  const long skipB = 64 * ldb;
  const int lofs = sr * 32 + kcd;

  floatx4 acc[4][4];
  #pragma unroll
  for (int i = 0; i < 4; ++i)
    #pragma unroll
    for (int j = 0; j < 4; ++j)
      acc[i][j] = (floatx4){0.f, 0.f, 0.f, 0.f};
  floatx4 accs[4];
  #pragma unroll
  for (int i = 0; i < 4; ++i) accs[i] = (floatx4){0.f, 0.f, 0.f, 0.f};
  const short8 b_ones = {0x3F80, 0x3F80, 0x3F80, 0x3F80,
                         0x3F80, 0x3F80, 0x3F80, 0x3F80};  // bf16 1.0 x8

  const int wr = (w >> 1) & 1, wc = w & 1;
  const int g = l >> 4, t = l & 15;
  const int swz = (g ^ ((t >> 1) & 3)) << 3;           // swizzled ds_read slot
  const int aoff = (wr * 64 + t) * 32 + swz;
  const int boff = (wc * 64 + t) * 32 + swz;

  const int nt = K >> 5;

  // prologue: stage tile 0 into buf 0 (4 loads in flight)
  cp16_g2l(&sA[0][lofs],           gA);
  cp16_g2l(&sA[0][lofs] + 64 * 32, gA + skipA);
  cp16_g2l(&sB[0][lofs],           gB);
  cp16_g2l(&sB[0][lofs] + 64 * 32, gB + skipB);

  int bufc = 0;
  for (int kt = 0; kt < nt; ++kt) {
    const int nxtb = (bufc == 2) ? 0 : bufc + 1;
    if (kt + 1 < nt) {
      const long oA = (long)(kt + 1) * koA;
      const long oB = (long)(kt + 1) << 5;
      cp16_g2l(&sA[nxtb][lofs],           gA + oA);
      cp16_g2l(&sA[nxtb][lofs] + 64 * 32, gA + oA + skipA);
      cp16_g2l(&sB[nxtb][lofs],           gB + oB);
      cp16_g2l(&sB[nxtb][lofs] + 64 * 32, gB + oB + skipB);
      asm volatile("s_waitcnt vmcnt(4)" ::: "memory");  // tile kt landed
    } else {
      asm volatile("s_waitcnt vmcnt(0)" ::: "memory");  // final tile landed
    }
    asm volatile("s_barrier" ::: "memory");             // all waves ready

    const bf16* cA = &sA[bufc][0];
    const bf16* cB = &sB[bufc][0];
    short8 a[4], b[4];
    #pragma unroll
    for (int m = 0; m < 4; ++m) a[m] = *(const short8*)(cA + aoff + m * 512);
    #pragma unroll
    for (int n = 0; n < 4; ++n) b[n] = *(const short8*)(cB + boff + n * 512);
    #pragma unroll
    for (int m = 0; m < 4; ++m)
      #pragma unroll
      for (int n = 0; n < 4; ++n)
        acc[m][n] = __builtin_amdgcn_mfma_f32_16x16x32_bf16(a[m], b[n], acc[m][n], 0, 0, 0);
    if constexpr (ONES) {
      #pragma unroll
      for (int m = 0; m < 4; ++m)
        accs[m] = __builtin_amdgcn_mfma_f32_16x16x32_bf16(a[m], b_ones, accs[m], 0, 0, 0);
    }
    bufc = nxtb;
  }

  // epilogue: C/D layout col = lane&15, row = (lane>>4)*4 + r  [m89]
  const long orow = row0 + wr * 64 + (g << 2);
  const long ocol = col0 + wc * 64 + t;

  if constexpr (MODE == 0 || MODE == 4) {
    bf16* O = (bf16*)out + (long)bz * sOb;
    float bv4[4];
    #pragma unroll
    for (int n = 0; n < 4; ++n) bv4[n] = bias[ocol + n * 16];
    #pragma unroll
    for (int m = 0; m < 4; ++m) {
      #pragma unroll
      for (int r = 0; r < 4; ++r) {
        bf16* Or = O + (orow + m * 16 + r) * (long)N + ocol;
        #pragma unroll
        for (int n = 0; n < 4; ++n) {      // n innermost: row-dense stores
          float vv = acc[m][n][r] + bv4[n];
          if constexpr (MODE == 4) vv = gelu_exact(vv);
          Or[n * 16] = __float2bfloat16(vv);
        }
      }
    }
  } else if constexpr (MODE == 7) {        // bf16 = acc + bias + f32 resid
    bf16* O = (bf16*)out;
    float bv4[4];
    #pragma unroll
    for (int n = 0; n < 4; ++n) bv4[n] = bias[ocol + n * 16];
    #pragma unroll
    for (int m = 0; m < 4; ++m) {
      #pragma unroll
      for (int r = 0; r < 4; ++r) {
        const long rb = (orow + m * 16 + r) * (long)N + ocol;
        #pragma unroll
        for (int n = 0; n < 4; ++n)
          O[rb + n * 16] =
              __float2bfloat16(acc[m][n][r] + bv4[n] + residf[rb + n * 16]);
      }
    }
  } else if constexpr (MODE == 8) {        // f32 = acc + bias + bf16 resid
    float* O = (float*)out;
    float bv4[4];
    #pragma unroll
    for (int n = 0; n < 4; ++n) bv4[n] = bias[ocol + n * 16];
    #pragma unroll
    for (int m = 0; m < 4; ++m) {
      #pragma unroll
      for (int r = 0; r < 4; ++r) {
        const long rb = (orow + m * 16 + r) * (long)N + ocol;
        #pragma unroll
        for (int n = 0; n < 4; ++n)
          O[rb + n * 16] = acc[m][n][r] + bv4[n] +
                           __bfloat162float(residb[rb + n * 16]);
      }
    }
  } else if constexpr (MODE == 5) {
    bf16* O = (bf16*)out + (long)bz * sOb;
    #pragma unroll
    for (int m = 0; m < 4; ++m) {
      #pragma unroll
      for (int r = 0; r < 4; ++r) {
        const long rr = orow + m * 16 + r;
        const float inv = 1.0f / accs[m][r];   // ones-MFMA row sum (exact
        bf16* Or = O + rr * (long)N + ocol;    // same rows as this lane)
        #pragma unroll
        for (int n = 0; n < 4; ++n)
          Or[n * 16] = __float2bfloat16(acc[m][n][r] * inv);
      }
    }
  } else {  // MODE 6: panel-16 exp output; panel stride = N*16 (N == P rows)
    bf16* O = (bf16*)out + (long)bz * sOb;
    const long pb = (col0 >> 4) + wc * 4;              // panel index base
    #pragma unroll
    for (int n = 0; n < 4; ++n) {                      // n outer: panel-dense
      bf16* Opan = O + (pb + n) * ((long)N * 16) + t;
      #pragma unroll
      for (int m = 0; m < 4; ++m) {
        #pragma unroll
        for (int r = 0; r < 4; ++r)
          Opan[(orow + m * 16 + r) * 16] =
              __float2bfloat16(__expf(acc[m][n][r] * scale));
      }
    }
  }
}

// row LayerNorm over D=768, fp32 in -> bf16 out
__global__ __launch_bounds__(256)
void ln_kernel(const float* __restrict__ X, const float* __restrict__ G,
               const float* __restrict__ Bv, bf16* __restrict__ H)
{
  const int tid = threadIdx.x;
  const long row = blockIdx.x;
  const float* xr = X + row * 768;
  const float v0 = xr[tid], v1 = xr[tid + 256], v2 = xr[tid + 512];
  float s = v0 + v1 + v2;
  float s2 = v0 * v0 + v1 * v1 + v2 * v2;
  #pragma unroll
  for (int o = 32; o > 0; o >>= 1) {
    s += __shfl_xor(s, o);
    s2 += __shfl_xor(s2, o);
  }
  __shared__ float red[8];
  const int w = tid >> 6, l = tid & 63;
  if (l == 0) { red[w] = s; red[w + 4] = s2; }
  __syncthreads();
  s = red[0] + red[1] + red[2] + red[3];
  s2 = red[4] + red[5] + red[6] + red[7];
  const float mu = s * (1.f / 768.f);
  const float var = s2 * (1.f / 768.f) - mu * mu;
  const float rstd = rsqrtf(var + 1e-5f);
  bf16* hr = H + row * 768;
  hr[tid]       = __float2bfloat16((v0 - mu) * rstd * G[tid]       + Bv[tid]);
  hr[tid + 256] = __float2bfloat16((v1 - mu) * rstd * G[tid + 256] + Bv[tid + 256]);
  hr[tid + 512] = __float2bfloat16((v2 - mu) * rstd * G[tid + 512] + Bv[tid + 512]);
}

// row LayerNorm over D=768, bf16 in -> bf16 out
__global__ __launch_bounds__(256)
void lnb_kernel(const bf16* __restrict__ X, const float* __restrict__ G,
                const float* __restrict__ Bv, bf16* __restrict__ H)
{
  const int tid = threadIdx.x;
  const long row = blockIdx.x;
  const bf16* xr = X + row * 768;
  const float v0 = __bfloat162float(xr[tid]);
  const float v1 = __bfloat162float(xr[tid + 256]);
  const float v2 = __bfloat162float(xr[tid + 512]);
  float s = v0 + v1 + v2;
  float s2 = v0 * v0 + v1 * v1 + v2 * v2;
  #pragma unroll
  for (int o = 32; o > 0; o >>= 1) {
    s += __shfl_xor(s, o);
    s2 += __shfl_xor(s2, o);
  }
  __shared__ float red[8];
  const int w = tid >> 6, l = tid & 63;
  if (l == 0) { red[w] = s; red[w + 4] = s2; }
  __syncthreads();
  s = red[0] + red[1] + red[2] + red[3];
  s2 = red[4] + red[5] + red[6] + red[7];
  const float mu = s * (1.f / 768.f);
  const float var = s2 * (1.f / 768.f) - mu * mu;
  const float rstd = rsqrtf(var + 1e-5f);
  bf16* hr = H + row * 768;
  hr[tid]       = __float2bfloat16((v0 - mu) * rstd * G[tid]       + Bv[tid]);
  hr[tid + 256] = __float2bfloat16((v1 - mu) * rstd * G[tid + 256] + Bv[tid + 256]);
  hr[tid + 512] = __float2bfloat16((v2 - mu) * rstd * G[tid + 512] + Bv[tid + 512]);
}

// Wt[n][k] = bf16(W[k][n]) ; W fp32 [K][N]. block (32,8)
__global__ void transpose_w(const float* __restrict__ W, bf16* __restrict__ Wt,
                            int K, int N)
{
  __shared__ float tile[32][33];
  const int n0 = blockIdx.x * 32, k0 = blockIdx.y * 32;
  const int tx = threadIdx.x, ty = threadIdx.y;
  #pragma unroll
  for (int j = ty; j < 32; j += 8)
    tile[j][tx] = W[(long)(k0 + j) * N + n0 + tx];
  __syncthreads();
  #pragma unroll
  for (int j = ty; j < 32; j += 8)
    Wt[(long)(n0 + j) * K + k0 + tx] = __float2bfloat16(tile[tx][j]);
}

// Vt[b][d][s] = qkv[(b*2048+s)*2304 + 1536 + d]  (bf16 v-slice of fused qkv)
__global__ void transpose_v(const bf16* __restrict__ QKV, bf16* __restrict__ Vt)
{
  __shared__ bf16 tile[32][33];
  const int d0 = blockIdx.x * 32, s0 = blockIdx.y * 32, b = blockIdx.z;
  const int tx = threadIdx.x, ty = threadIdx.y;
  #pragma unroll
  for (int j = ty; j < 32; j += 8)
    tile[j][tx] = QKV[((long)b * 2048 + s0 + j) * 2304 + 1536 + d0 + tx];
  __syncthreads();
  #pragma unroll
  for (int j = ty; j < 32; j += 8)
    Vt[(long)b * 768 * 2048 + (long)(d0 + j) * 2048 + s0 + tx] = tile[tx][j];
}

// concat 3x768 fp32 biases
__global__ void concat3(const float* __restrict__ a, const float* __restrict__ b,
                        const float* __restrict__ c, float* __restrict__ o)
{
  const int i = threadIdx.x + blockIdx.x * 256;
  if (i < 768) { o[i] = a[i]; o[i + 768] = b[i]; o[i + 1536] = c[i]; }
}

extern "C" void kernel_launch(void* const* d_in, const int* in_sizes, int n_in,
                              void* d_out, int out_size, void* d_ws, size_t ws_size,
                              hipStream_t stream)
{
  const float* x     = (const float*)d_in[0];
  const float* ln1g  = (const float*)d_in[1];
  const float* ln1b  = (const float*)d_in[2];
  const float* ln2g  = (const float*)d_in[3];
  const float* ln2b  = (const float*)d_in[4];
  const float* Wq    = (const float*)d_in[5];
  const float* bq    = (const float*)d_in[6];
  const float* Wk    = (const float*)d_in[7];
  const float* bk    = (const float*)d_in[8];
  const float* Wv    = (const float*)d_in[9];
  const float* bvv   = (const float*)d_in[10];
  const float* Wo    = (const float*)d_in[11];
  const float* bo    = (const float*)d_in[12];
  const float* Wfc   = (const float*)d_in[13];
  const float* bfc   = (const float*)d_in[14];
  const float* Wproj = (const float*)d_in[15];
  const float* bproj = (const float*)d_in[16];
  float* out = (float*)d_out;

  constexpr int Bz = 8, S = 2048, D = 768, Hh = 3072, QKVN = 3 * D;
  constexpr long Mtot = (long)Bz * S;  // 16384

  char* ws = (char*)d_ws;
  size_t off = 0;
  auto alloc = [&](size_t bytes) -> char* {
    char* p = ws + off;
    off += (bytes + 255) & ~(size_t)255;
    return p;
  };
  bf16* wqkvT = (bf16*)alloc((size_t)QKVN * D * 2);
  bf16* woT   = (bf16*)alloc((size_t)D * D * 2);
  bf16* wfcT  = (bf16*)alloc((size_t)Hh * D * 2);
  bf16* wprT  = (bf16*)alloc((size_t)D * Hh * 2);
  float* bqkv = (float*)alloc((size_t)QKVN * 4);
  bf16* hb    = (bf16*)alloc((size_t)Mtot * D * 2);
  bf16* qkv   = (bf16*)alloc((size_t)Mtot * QKVN * 2);
  bf16* vtb   = (bf16*)alloc((size_t)Mtot * D * 2);
  bf16* yb    = (bf16*)alloc((size_t)Mtot * D * 2);
  // x1 (bf16 residual stream) ALIASES qkv: qkv is dead after the last scores
  // GEMM; Wo (which writes x1) launches strictly after it.
  bf16* x1b = qkv;

  int nbat = Bz;
  size_t region = (size_t)nbat * S * S * 2;              // p (bf16, panel-16)
  const size_t mbytes = (size_t)Mtot * Hh * 2;           // MLP hidden bf16
  if (region < mbytes) region = mbytes;
  if (off + region > ws_size) {                          // fallback: per-batch
    nbat = 1;
    region = mbytes;
  }
  char* reg = alloc(region);
  bf16* attn = (bf16*)reg;
  bf16* mb = (bf16*)reg;  // aliases attn (used after attention done)

  const dim3 tb(32, 8);

  // weight prep (bf16, [N][K]); q/k/v stacked into wqkvT rows 0/768/1536
  transpose_w<<<dim3(D / 32, D / 32), tb, 0, stream>>>(Wq, wqkvT, D, D);
  transpose_w<<<dim3(D / 32, D / 32), tb, 0, stream>>>(Wk, wqkvT + (size_t)D * D, D, D);
  transpose_w<<<dim3(D / 32, D / 32), tb, 0, stream>>>(Wv, wqkvT + 2 * (size_t)D * D, D, D);
  transpose_w<<<dim3(D / 32, D / 32), tb, 0, stream>>>(Wo, woT, D, D);
  transpose_w<<<dim3(Hh / 32, D / 32), tb, 0, stream>>>(Wfc, wfcT, D, Hh);
  transpose_w<<<dim3(D / 32, Hh / 32), tb, 0, stream>>>(Wproj, wprT, Hh, D);
  concat3<<<3, 256, 0, stream>>>(bq, bk, bvv, bqkv);

  // LN1 -> h (bf16)
  ln_kernel<<<(int)Mtot, 256, 0, stream>>>(x, ln1g, ln1b, hb);

  // fused QKV projection: [16384,768] @ [2304,768]^T -> [16384,2304]
  gemm_bt<0><<<dim3(Mtot / 128, QKVN / 128, 1), 256, 0, stream>>>(
      hb, 0, D, wqkvT, 0, D, bqkv, nullptr, nullptr, qkv, 0, QKVN, D, 1.f);
  transpose_v<<<dim3(D / 32, S / 32, Bz), tb, 0, stream>>>(qkv, vtb);

  // attention: p = exp(QK^T*sc) (panel-16) -> PV with ones-MFMA row-sums
  const float sc = 0.03608439182435161f;  // 1/sqrt(768)
  for (int g0 = 0; g0 < Bz; g0 += nbat) {
    const bf16* qg  = qkv + (long)g0 * S * QKVN;          // q slice, lda=2304
    const bf16* kg  = qkv + (long)g0 * S * QKVN + D;      // k slice, ldb=2304
    const bf16* vtg = vtb + (long)g0 * D * S;
    bf16* yg = yb + (long)g0 * S * D;
    gemm_bt<6><<<dim3(S / 128, S / 128, nbat), 256, 0, stream>>>(
        qg, (long)S * QKVN, QKVN, kg, (long)S * QKVN, QKVN, nullptr, nullptr,
        nullptr, attn, (long)S * S, S, D, sc);
    gemm_bt<5><<<dim3(S / 128, D / 128, nbat), 256, 0, stream>>>(
        attn, (long)S * S, S, vtg, (long)D * S, S, nullptr, nullptr,
        nullptr, yg, (long)S * D, D, S, 1.f);
  }

  // out-projection + residual -> x1 (bf16 residual stream, aliases dead qkv)
  gemm_bt<7><<<dim3(Mtot / 128, D / 128, 1), 256, 0, stream>>>(
      yb, 0, D, woT, 0, D, bo, x, nullptr, x1b, 0, D, D, 1.f);

  // LN2 -> h2 (bf16, reuse hb)
  lnb_kernel<<<(int)Mtot, 256, 0, stream>>>(x1b, ln2g, ln2b, hb);

  // MLP: fc + exact GELU -> mb (bf16), then proj + bf16 resid -> f32 d_out
  gemm_bt<4><<<dim3(Mtot / 128, Hh / 128, 1), 256, 0, stream>>>(
      hb, 0, D, wfcT, 0, D, bfc, nullptr, nullptr, mb, 0, Hh, D, 1.f);
  gemm_bt<8><<<dim3(Mtot / 128, D / 128, 1), 256, 0, stream>>>(
      mb, 0, Hh, wprT, 0, Hh, bproj, nullptr, x1b, out, 0, D, Hh, 1.f);
}